// Round 9
// baseline (1148.833 us; speedup 1.0000x reference)
//
#include <hip/hip_runtime.h>
#include <cstdint>
#include <cstddef>

#define E_EDGES 200000
#define NP 100000
#define NF 100000
#define NPORT 50000
#define NTOT 250000
#define TOTDEG 850000
#define GPOOL 128
#define NPART_C 2
#define SPP_C 425000
#define NPART_F 4
#define SPP_F 212500
#define CAPW 128

typedef __attribute__((ext_vector_type(8))) short bf16x8;
typedef __attribute__((ext_vector_type(4))) float f32x4;

__device__ __forceinline__ float bf2f(unsigned short u) {
    return __uint_as_float(((unsigned int)u) << 16);
}
__device__ __forceinline__ unsigned short f2bf(float f) {
    unsigned int x = __float_as_uint(f);
    return (unsigned short)((x + 0x7fffu + ((x >> 16) & 1u)) >> 16);
}

struct EiPtrs {
    const int* p[10];
};

// seg layout (dst-major): proc dst v: segs 5v+r; file: 500000+2v+r; port: 700000+3v+r.
// list[] stores GLOBAL src id (proc +0, file +100000, port +200000).
__device__ __forceinline__ int seg_of(int r, int dst) {
    if (r < 5) return dst * 5 + r;
    if (r < 7) return 500000 + dst * 2 + (r - 5);
    return 700000 + dst * 3 + (r - 7);
}
__device__ __forceinline__ int srcbase_of(int r) {
    return (r <= 1) ? 100000 : (r == 2 || r >= 8) ? 200000 : 0;
}

// ---------------------------------------------------------------- init (fused)
__global__ __launch_bounds__(256) void k_init(const float* __restrict__ W0,
                                              const float* __restrict__ W1,
                                              const float* __restrict__ W2,
                                              unsigned short* __restrict__ WT0,
                                              unsigned short* __restrict__ WT1,
                                              unsigned short* __restrict__ WT2,
                                              int* __restrict__ cursor,
                                              float* __restrict__ pooled) {
    int idx = blockIdx.x * 256 + threadIdx.x;
    if (idx < TOTDEG) cursor[idx] = 0;
    if (idx < GPOOL * 128) pooled[idx] = 0.f;
    if (idx < 128 * 64) {
        int col = idx / 64, k = idx - col * 64;
        WT0[idx] = f2bf(W0[k * 128 + col]);
    }
    if (idx < 128 * 128) {
        int col = idx >> 7, k = idx & 127;
        WT1[idx] = f2bf(W1[k * 128 + col]);
        WT2[idx] = f2bf(W2[k * 128 + col]);
    }
}

// ---------------------------------------------------------------- CSR build
__global__ __launch_bounds__(256) void k_count_all(EiPtrs eis, int* __restrict__ deg) {
    int r = blockIdx.y;
    int e = blockIdx.x * 256 + threadIdx.x;
    if (e >= E_EDGES) return;
    int seg = seg_of(r, eis.p[r][E_EDGES + e]);
    int lo = blockIdx.z * SPP_C;
    if (seg < lo || seg >= lo + SPP_C) return;
    atomicAdd(&deg[seg], 1);
}

__global__ __launch_bounds__(256) void k_scan_partial(const int* __restrict__ deg,
                                                      int* __restrict__ bsum) {
    int t = threadIdx.x, b = blockIdx.x;
    int base = b * 1024 + t * 4;
    int sv = 0;
#pragma unroll
    for (int i = 0; i < 4; i++) {
        int idx = base + i;
        if (idx < TOTDEG) sv += deg[idx];
    }
#pragma unroll
    for (int msk = 1; msk < 64; msk <<= 1) sv += __shfl_xor(sv, msk);
    __shared__ int ws[4];
    if ((t & 63) == 0) ws[t >> 6] = sv;
    __syncthreads();
    if (t == 0) bsum[b] = ws[0] + ws[1] + ws[2] + ws[3];
}

__global__ __launch_bounds__(1024) void k_scan_bsums(int* __restrict__ bsum, int nb) {
    __shared__ int lds[1024];
    int t = threadIdx.x;
    int v = (t < nb) ? bsum[t] : 0;
    lds[t] = v;
    __syncthreads();
    for (int dd = 1; dd < 1024; dd <<= 1) {
        int u = (t >= dd) ? lds[t - dd] : 0;
        __syncthreads();
        lds[t] += u;
        __syncthreads();
    }
    if (t < nb) bsum[t] = lds[t] - v;  // exclusive
}

// writes offs AND cursor (cursor = fill's atomic start positions)
__global__ __launch_bounds__(256) void k_scan_final(const int* __restrict__ deg,
                                                    const int* __restrict__ bsum,
                                                    int* __restrict__ offs,
                                                    int* __restrict__ cursor) {
    int t = threadIdx.x, b = blockIdx.x;
    int base = b * 1024 + t * 4;
    int v[4];
    int tot = 0;
#pragma unroll
    for (int i = 0; i < 4; i++) {
        int idx = base + i;
        v[i] = (idx < TOTDEG) ? deg[idx] : 0;
        tot += v[i];
    }
    int lane = t & 63, w = t >> 6;
    int x = tot;
#pragma unroll
    for (int dd = 1; dd < 64; dd <<= 1) {
        int u = __shfl_up(x, dd);
        if (lane >= dd) x += u;
    }
    __shared__ int wt[4];
    if (lane == 63) wt[w] = x;
    __syncthreads();
    int wbase = 0;
#pragma unroll
    for (int j = 0; j < 4; j++)
        if (j < w) wbase += wt[j];
    int run = bsum[b] + wbase + (x - tot);
#pragma unroll
    for (int i = 0; i < 4; i++) {
        int idx = base + i;
        if (idx <= TOTDEG) offs[idx] = run;
        if (idx < TOTDEG) cursor[idx] = run;
        run += v[i];
    }
}

__global__ __launch_bounds__(256) void k_fill_all(EiPtrs eis, int* __restrict__ cursor,
                                                  int* __restrict__ list) {
    int r = blockIdx.y;
    int e = blockIdx.x * 256 + threadIdx.x;
    if (e >= E_EDGES) return;
    const int* ei = eis.p[r];
    int seg = seg_of(r, ei[E_EDGES + e]);
    int lo = blockIdx.z * SPP_F;
    if (seg < lo || seg >= lo + SPP_F) return;
    int pos = atomicAdd(&cursor[seg], 1);
    list[pos] = ei[e] + srcbase_of(r);  // global src id
}

// ---------------------------------------------------------------- MFMA GEMM body
template <int K, bool BF16IN>
__device__ __forceinline__ void gemm_body(const void* __restrict__ xv,
                                          const unsigned short* __restrict__ WT,
                                          const float* __restrict__ avs,
                                          const float* __restrict__ avd,
                                          unsigned short* __restrict__ h,
                                          float* __restrict__ s, float* __restrict__ d,
                                          int N, int row0) {
    constexpr int NQ = K / 32;
    __shared__ float csmem[64][130];  // aliased: WT tile first, C tile after
    char* sw = (char*)&csmem[0][0];
    int tid = threadIdx.x;
    int w = tid >> 6, l = tid & 63;

    constexpr int WT_BYTES = 128 * K * 2;
#pragma unroll
    for (int i = tid * 16; i < WT_BYTES; i += 256 * 16) {
        uint4 v = *(const uint4*)((const char*)WT + i);
        int row = i / (2 * K);
        int addr = i ^ ((row & 7) << 4);
        *(uint4*)(sw + addr) = v;
    }

    int arow = row0 + w * 16 + (l & 15);
    bf16x8 afrag[NQ];
    if (arow < N) {
        if (BF16IN) {
            const unsigned short* x = (const unsigned short*)xv;
#pragma unroll
            for (int q = 0; q < NQ; ++q) {
                int kc = q * 32 + (l >> 4) * 8;
                afrag[q] = *(const bf16x8*)&x[(size_t)arow * K + kc];
            }
        } else {
            const float* x = (const float*)xv;
#pragma unroll
            for (int q = 0; q < NQ; ++q) {
                int kc = q * 32 + (l >> 4) * 8;
                float4 f0 = *(const float4*)&x[(size_t)arow * K + kc];
                float4 f1 = *(const float4*)&x[(size_t)arow * K + kc + 4];
                bf16x8 a;
                a[0] = (short)f2bf(f0.x);
                a[1] = (short)f2bf(f0.y);
                a[2] = (short)f2bf(f0.z);
                a[3] = (short)f2bf(f0.w);
                a[4] = (short)f2bf(f1.x);
                a[5] = (short)f2bf(f1.y);
                a[6] = (short)f2bf(f1.z);
                a[7] = (short)f2bf(f1.w);
                afrag[q] = a;
            }
        }
    } else {
#pragma unroll
        for (int q = 0; q < NQ; ++q) {
            bf16x8 z = {0, 0, 0, 0, 0, 0, 0, 0};
            afrag[q] = z;
        }
    }
    __syncthreads();

    f32x4 acc[8];
#pragma unroll
    for (int c = 0; c < 8; ++c) acc[c] = (f32x4){0.f, 0.f, 0.f, 0.f};

#pragma unroll
    for (int c = 0; c < 8; ++c) {
        int cabs = c * 16 + (l & 15);
        int base = cabs * (2 * K) + ((l >> 4) * 16);
        int swz = (cabs & 7) << 4;
#pragma unroll
        for (int q = 0; q < NQ; ++q) {
            int addr = (base + q * 64) ^ swz;
            bf16x8 b = *(const bf16x8*)(sw + addr);
            acc[c] = __builtin_amdgcn_mfma_f32_16x16x32_bf16(afrag[q], b, acc[c], 0, 0, 0);
        }
    }
    __syncthreads();  // all waves done reading WT; reuse LDS for C

    int crow = w * 16 + (l >> 4) * 4;
    int ccol = l & 15;
#pragma unroll
    for (int c = 0; c < 8; ++c)
#pragma unroll
        for (int r = 0; r < 4; ++r) csmem[crow + r][c * 16 + ccol] = acc[c][r];
    __syncthreads();

    int row = tid >> 2, cg = tid & 3;
    int grow = row0 + row;
    if (grow < N) {
        float sv = 0.f, dv = 0.f;
        unsigned short tmp[32];
#pragma unroll
        for (int i = 0; i < 32; ++i) {
            float v = csmem[row][cg * 32 + i];
            sv = fmaf(v, avs[cg * 32 + i], sv);
            dv = fmaf(v, avd[cg * 32 + i], dv);
            tmp[i] = f2bf(v);
        }
        unsigned short* hp = &h[(size_t)grow * 128 + cg * 32];
        *(uint4*)&hp[0] = *(uint4*)&tmp[0];
        *(uint4*)&hp[8] = *(uint4*)&tmp[8];
        *(uint4*)&hp[16] = *(uint4*)&tmp[16];
        *(uint4*)&hp[24] = *(uint4*)&tmp[24];
        sv += __shfl_xor(sv, 1);
        sv += __shfl_xor(sv, 2);
        dv += __shfl_xor(dv, 1);
        dv += __shfl_xor(dv, 2);
        if (cg == 0) {
            s[grow] = sv;
            d[grow] = dv;
        }
    }
}

// L0: all 3 node types in one dispatch (grid.y = type)
__global__ __launch_bounds__(256) void gemm_l0(const float* __restrict__ xp,
                                               const float* __restrict__ xf,
                                               const float* __restrict__ xpo,
                                               const unsigned short* __restrict__ WT,
                                               const float* __restrict__ avs,
                                               const float* __restrict__ avd,
                                               unsigned short* __restrict__ H,
                                               float* __restrict__ s_all,
                                               float* __restrict__ d_all) {
    int ty = blockIdx.y;
    const float* x;
    int N, rowoff;
    if (ty == 0) {
        x = xp;
        N = NP;
        rowoff = 0;
    } else if (ty == 1) {
        x = xf;
        N = NF;
        rowoff = NP;
    } else {
        x = xpo;
        N = NPORT;
        rowoff = NP + NF;
    }
    int row0 = blockIdx.x * 64;
    if (row0 >= N) return;
    gemm_body<64, false>(x, WT, avs, avd, H + (size_t)rowoff * 128, s_all + rowoff,
                         d_all + rowoff, N, row0);
}

__global__ __launch_bounds__(256) void gemm_big(const unsigned short* __restrict__ X,
                                                const unsigned short* __restrict__ WT,
                                                const float* __restrict__ avs,
                                                const float* __restrict__ avd,
                                                unsigned short* __restrict__ H,
                                                float* __restrict__ s_all,
                                                float* __restrict__ d_all) {
    gemm_body<128, true>(X, WT, avs, avd, H, s_all, d_all, NTOT, blockIdx.x * 64);
}

// ---------------------------------------------------------------- fused softmax+gather
// cold path: recompute weight for edge j when merged degree > CAPW (P ~ 0)
template <int NREL>
__device__ float slow_w(int j, const int* o, float dd, const int* __restrict__ list,
                        const float* __restrict__ s_all) {
    float w = 0.f;
#pragma unroll
    for (int r = 0; r < NREL; ++r) {
        if (j >= o[r] && j < o[r + 1]) {
            float m = -1e30f, den = 0.f;
            for (int k = o[r]; k < o[r + 1]; ++k) {
                float x = s_all[list[k]] + dd;
                x = (x >= 0.f) ? x : 0.2f * x;
                if (x > m) {
                    den = den * __expf(m - x) + 1.f;
                    m = x;
                } else {
                    den += __expf(x - m);
                }
            }
            float xj = s_all[list[j]] + dd;
            xj = (xj >= 0.f) ? xj : 0.2f * xj;
            w = __expf(xj - m) / fmaxf(den, 1e-16f);
        }
    }
    return w;
}

template <int NREL>
__device__ __forceinline__ void gather_one(int dst, int seg0, float inv_nrel, int lane,
                                           const int* __restrict__ offs,
                                           const int* __restrict__ list,
                                           const float* __restrict__ s_all,
                                           const float* __restrict__ d_all,
                                           const float* __restrict__ bias,
                                           const unsigned short* __restrict__ H,
                                           unsigned short* __restrict__ X,
                                           float* __restrict__ wl) {
    int o[NREL + 1];
#pragma unroll
    for (int i = 0; i <= NREL; ++i) o[i] = offs[seg0 + i];
    const int base = o[0], oend = o[NREL];
    const float dd = d_all[dst];
    // phase 1: per-segment online softmax (all lanes redundant), weights -> LDS
#pragma unroll
    for (int r = 0; r < NREL; ++r) {
        int s = o[r], e = o[r + 1];
        if (e <= s) continue;
        float m = -1e30f, den = 0.f;
        for (int j = s; j < e; ++j) {
            float x = s_all[list[j]] + dd;
            x = (x >= 0.f) ? x : 0.2f * x;
            if (x > m) {
                den = den * __expf(m - x) + 1.f;
                m = x;
            } else {
                den += __expf(x - m);
            }
        }
        float invd = 1.f / fmaxf(den, 1e-16f);
        for (int j = s + lane; j < e; j += 32) {
            float x = s_all[list[j]] + dd;
            x = (x >= 0.f) ? x : 0.2f * x;
            int idx = j - base;
            if (idx < CAPW) wl[idx] = __expf(x - m) * invd;
        }
    }
    __builtin_amdgcn_wave_barrier();  // keep ds_writes ahead of phase-2 ds_reads

    // phase 2: merged weighted gather (R5 structure: even/odd 16-lane halves)
    int half = lane >> 4, l16 = lane & 15;
    float a[8] = {0.f, 0.f, 0.f, 0.f, 0.f, 0.f, 0.f, 0.f};
    float b[8] = {0.f, 0.f, 0.f, 0.f, 0.f, 0.f, 0.f, 0.f};
    if (oend - base <= CAPW) {
        int j = base + half;
        for (; j + 2 < oend; j += 4) {
            int s0 = list[j], s1 = list[j + 2];
            float w0 = wl[j - base], w1 = wl[j + 2 - base];
            uint4 r0 = *(const uint4*)&H[(size_t)s0 * 128 + l16 * 8];
            uint4 r1 = *(const uint4*)&H[(size_t)s1 * 128 + l16 * 8];
            const unsigned short* u0 = (const unsigned short*)&r0;
            const unsigned short* u1 = (const unsigned short*)&r1;
#pragma unroll
            for (int k = 0; k < 8; ++k) a[k] = fmaf(w0, bf2f(u0[k]), a[k]);
#pragma unroll
            for (int k = 0; k < 8; ++k) b[k] = fmaf(w1, bf2f(u1[k]), b[k]);
        }
        for (; j < oend; j += 2) {
            int s0 = list[j];
            float w0 = wl[j - base];
            uint4 r0 = *(const uint4*)&H[(size_t)s0 * 128 + l16 * 8];
            const unsigned short* u0 = (const unsigned short*)&r0;
#pragma unroll
            for (int k = 0; k < 8; ++k) a[k] = fmaf(w0, bf2f(u0[k]), a[k]);
        }
    } else {  // cold, correct fallback
        for (int j = base + half; j < oend; j += 2) {
            int s0 = list[j];
            float w0 = slow_w<NREL>(j, o, dd, list, s_all);
            uint4 r0 = *(const uint4*)&H[(size_t)s0 * 128 + l16 * 8];
            const unsigned short* u0 = (const unsigned short*)&r0;
#pragma unroll
            for (int k = 0; k < 8; ++k) a[k] = fmaf(w0, bf2f(u0[k]), a[k]);
        }
    }
#pragma unroll
    for (int k = 0; k < 8; ++k) {
        a[k] += b[k];
        a[k] += __shfl_xor(a[k], 16);
    }
    int c0 = l16 * 8 + half * 4;
    float4 b4 = *(const float4*)&bias[c0];
    float v0 = fmaf(a[half * 4 + 0], inv_nrel, b4.x);
    float v1 = fmaf(a[half * 4 + 1], inv_nrel, b4.y);
    float v2 = fmaf(a[half * 4 + 2], inv_nrel, b4.z);
    float v3 = fmaf(a[half * 4 + 3], inv_nrel, b4.w);
    v0 = (v0 >= 0.f) ? v0 : 0.01f * v0;
    v1 = (v1 >= 0.f) ? v1 : 0.01f * v1;
    v2 = (v2 >= 0.f) ? v2 : 0.01f * v2;
    v3 = (v3 >= 0.f) ? v3 : 0.01f * v3;
    ushort4 ov;
    ov.x = f2bf(v0);
    ov.y = f2bf(v1);
    ov.z = f2bf(v2);
    ov.w = f2bf(v3);
    *(ushort4*)&X[(size_t)dst * 128 + c0] = ov;
}

__global__ __launch_bounds__(256) void k_gather(const int* __restrict__ offs,
                                                const int* __restrict__ list,
                                                const float* __restrict__ s_all,
                                                const float* __restrict__ d_all,
                                                const float* __restrict__ bias,
                                                const unsigned short* __restrict__ H,
                                                unsigned short* __restrict__ X) {
    __shared__ float wlds[8][CAPW];
    int grp = threadIdx.x >> 5, lane = threadIdx.x & 31;
    int dst = blockIdx.x * 8 + grp;
    if (dst >= NTOT) return;
    float* wl = wlds[grp];
    // type boundaries (100000, 200000) are multiples of 8 -> block-uniform branch
    if (dst < NP)
        gather_one<5>(dst, dst * 5, 0.2f, lane, offs, list, s_all, d_all, bias, H, X, wl);
    else if (dst < NP + NF)
        gather_one<2>(dst, 500000 + (dst - NP) * 2, 0.5f, lane, offs, list, s_all, d_all,
                      bias, H, X, wl);
    else
        gather_one<3>(dst, 700000 + (dst - NP - NF) * 3, 1.f / 3.f, lane, offs, list,
                      s_all, d_all, bias, H, X, wl);
}

// ---------------------------------------------------------------- pooling (all types)
__global__ __launch_bounds__(128) void pool_all(const unsigned short* __restrict__ X,
                                                const int* __restrict__ bp,
                                                const int* __restrict__ bf,
                                                const int* __restrict__ bpo,
                                                float* __restrict__ pooled) {
    int t = threadIdx.x;
    int start = blockIdx.x * 128;
    int end = min(start + 128, NTOT);
    if (start >= end) return;
    auto bat = [&](int i) {
        return (i < NP) ? bp[i] : (i < NP + NF) ? bf[i - NP] : bpo[i - NP - NF];
    };
    float acc = 0.f;
    int g = bat(start);
    for (int i = start; i < end; ++i) {
        int gi = bat(i);
        if (gi != g) {
            atomicAdd(&pooled[(size_t)g * 128 + t], acc);
            acc = 0.f;
            g = gi;
        }
        acc += bf2f(X[(size_t)i * 128 + t]);
    }
    atomicAdd(&pooled[(size_t)g * 128 + t], acc);
}

// ---------------------------------------------------------------- final MLP
__global__ __launch_bounds__(128) void k_mlp(const float* __restrict__ pooled,
                                             const float* __restrict__ w1,
                                             const float* __restrict__ b1,
                                             const float* __restrict__ w2,
                                             const float* __restrict__ b2,
                                             float* __restrict__ out) {
    __shared__ float p[128];
    __shared__ float r0[2], r1[2];
    int g = blockIdx.x, t = threadIdx.x;
    p[t] = pooled[g * 128 + t];
    __syncthreads();
    float acc = b1[t];
    for (int k = 0; k < 128; ++k) acc = fmaf(p[k], w1[k * 128 + t], acc);
    float v0 = acc * w2[t * 2 + 0];
    float v1 = acc * w2[t * 2 + 1];
#pragma unroll
    for (int msk = 1; msk < 64; msk <<= 1) {
        v0 += __shfl_xor(v0, msk);
        v1 += __shfl_xor(v1, msk);
    }
    if ((t & 63) == 0) {
        r0[t >> 6] = v0;
        r1[t >> 6] = v1;
    }
    __syncthreads();
    if (t == 0) {
        out[g * 2 + 0] = r0[0] + r0[1] + b2[0];
        out[g * 2 + 1] = r1[0] + r1[1] + b2[1];
    }
}

// workspace-too-small diagnostic: report ws_size via the absmax channel
__global__ void k_ws_debug(float* out, int n, float val) {
    int i = blockIdx.x * 256 + threadIdx.x;
    if (i < n) out[i] = val;
}

// ---------------------------------------------------------------- launch
extern "C" void kernel_launch(void* const* d_in, const int* in_sizes, int n_in,
                              void* d_out, int out_size, void* d_ws, size_t ws_size,
                              hipStream_t stream) {
    const float* x_p0 = (const float*)d_in[0];
    const float* x_f0 = (const float*)d_in[1];
    const float* x_po0 = (const float*)d_in[2];
    const float* Wl[3] = {(const float*)d_in[3], (const float*)d_in[7],
                          (const float*)d_in[11]};
    const float* asl[3] = {(const float*)d_in[4], (const float*)d_in[8],
                           (const float*)d_in[12]};
    const float* adl[3] = {(const float*)d_in[5], (const float*)d_in[9],
                           (const float*)d_in[13]};
    const float* bl[3] = {(const float*)d_in[6], (const float*)d_in[10],
                          (const float*)d_in[14]};
    const float* lin1_w = (const float*)d_in[15];
    const float* lin1_b = (const float*)d_in[16];
    const float* lin2_w = (const float*)d_in[17];
    const float* lin2_b = (const float*)d_in[18];
    // relation order: 0..4 dst=process, 5..6 dst=file, 7..9 dst=port
    EiPtrs eis;
    eis.p[0] = (const int*)d_in[20];  // rev_access  (file -> proc)
    eis.p[1] = (const int*)d_in[22];  // rev_same_as (file -> proc)
    eis.p[2] = (const int*)d_in[24];  // rev_bind    (port -> proc)
    eis.p[3] = (const int*)d_in[27];  // create      (proc -> proc)
    eis.p[4] = (const int*)d_in[28];  // rev_create  (proc -> proc)
    eis.p[5] = (const int*)d_in[19];  // access      (proc -> file)
    eis.p[6] = (const int*)d_in[21];  // same_as     (proc -> file)
    eis.p[7] = (const int*)d_in[23];  // bind        (proc -> port)
    eis.p[8] = (const int*)d_in[25];  // session     (port -> port)
    eis.p[9] = (const int*)d_in[26];  // rev_session (port -> port)
    const int* batch_p = (const int*)d_in[29];
    const int* batch_f = (const int*)d_in[30];
    const int* batch_po = (const int*)d_in[31];
    float* out = (float*)d_out;

    // workspace layout (16B aligned)
    char* w = (char*)d_ws;
    size_t off = 0;
    int* offs = (int*)(w + off);      off += (size_t)850004 * 4;
    int* cursor = (int*)(w + off);    off += (size_t)TOTDEG * 4;
    int* list = (int*)(w + off);      off += (size_t)10 * E_EDGES * 4;
    int* bsum = (int*)(w + off);      off += 4096;
    unsigned short* H = (unsigned short*)(w + off); off += (size_t)NTOT * 128 * 2;
    unsigned short* X = (unsigned short*)(w + off); off += (size_t)NTOT * 128 * 2;
    float* s_all = (float*)(w + off); off += (size_t)NTOT * 4;
    float* d_all = (float*)(w + off); off += (size_t)NTOT * 4;
    float* pooled = (float*)(w + off); off += (size_t)GPOOL * 128 * 4;
    unsigned short* WT0 = (unsigned short*)(w + off); off += (size_t)128 * 64 * 2;
    unsigned short* WT1 = (unsigned short*)(w + off); off += (size_t)128 * 128 * 2;
    unsigned short* WT2 = (unsigned short*)(w + off); off += (size_t)128 * 128 * 2;
    if (ws_size < off) {
        k_ws_debug<<<(out_size + 255) / 256, 256, 0, stream>>>(out, out_size,
                                                               (float)ws_size);
        return;
    }

    k_init<<<(TOTDEG + 255) / 256, 256, 0, stream>>>(Wl[0], Wl[1], Wl[2], WT0, WT1, WT2,
                                                     cursor, pooled);

    int eb = (E_EDGES + 255) / 256;
    k_count_all<<<dim3(eb, 10, NPART_C), 256, 0, stream>>>(eis, cursor);
    int nb = (TOTDEG + 1 + 1023) / 1024;  // 831
    k_scan_partial<<<nb, 256, 0, stream>>>(cursor, bsum);
    k_scan_bsums<<<1, 1024, 0, stream>>>(bsum, nb);
    k_scan_final<<<nb, 256, 0, stream>>>(cursor, bsum, offs, cursor);
    k_fill_all<<<dim3(eb, 10, NPART_F), 256, 0, stream>>>(eis, cursor, list);

    for (int L = 0; L < 3; ++L) {
        if (L == 0) {
            gemm_l0<<<dim3((NP + 63) / 64, 3), 256, 0, stream>>>(
                x_p0, x_f0, x_po0, WT0, asl[0], adl[0], H, s_all, d_all);
        } else {
            const unsigned short* WTL = (L == 1) ? WT1 : WT2;
            gemm_big<<<(NTOT + 63) / 64, 256, 0, stream>>>(X, WTL, asl[L], adl[L], H,
                                                           s_all, d_all);
        }
        k_gather<<<(NTOT + 7) / 8, 256, 0, stream>>>(offs, list, s_all, d_all, bl[L], H,
                                                     X);
    }

    pool_all<<<(NTOT + 127) / 128, 128, 0, stream>>>(X, batch_p, batch_f, batch_po,
                                                     pooled);

    k_mlp<<<GPOOL, 128, 0, stream>>>(pooled, lin1_w, lin1_b, lin2_w, lin2_b, out);
}

// Round 10
// 861.343 us; speedup vs baseline: 1.3338x; 1.3338x over previous
//
#include <hip/hip_runtime.h>
#include <cstdint>
#include <cstddef>

#define E_EDGES 200000
#define NP 100000
#define NF 100000
#define NPORT 50000
#define NTOT 250000
#define TOTDEG 850000
#define GPOOL 128
#define NPART_C 2
#define SPP_C 425000
#define NPART_F 4
#define SPP_F 212500

typedef __attribute__((ext_vector_type(8))) short bf16x8;
typedef __attribute__((ext_vector_type(4))) float f32x4;

__device__ __forceinline__ float bf2f(unsigned short u) {
    return __uint_as_float(((unsigned int)u) << 16);
}
__device__ __forceinline__ unsigned short f2bf(float f) {
    unsigned int x = __float_as_uint(f);
    return (unsigned short)((x + 0x7fffu + ((x >> 16) & 1u)) >> 16);
}

struct EiPtrs {
    const int* p[10];
};

// seg layout (dst-major): proc dst v: segs 5v+r; file: 500000+2v+r; port: 700000+3v+r.
// list[] stores GLOBAL src id (proc +0, file +100000, port +200000).
__device__ __forceinline__ int seg_of(int r, int dst) {
    if (r < 5) return dst * 5 + r;
    if (r < 7) return 500000 + dst * 2 + (r - 5);
    return 700000 + dst * 3 + (r - 7);
}
__device__ __forceinline__ int srcbase_of(int r) {
    return (r <= 1) ? 100000 : (r == 2 || r >= 8) ? 200000 : 0;
}

// ---------------------------------------------------------------- init (fused)
__global__ __launch_bounds__(256) void k_init(const float* __restrict__ W0,
                                              const float* __restrict__ W1,
                                              const float* __restrict__ W2,
                                              unsigned short* __restrict__ WT0,
                                              unsigned short* __restrict__ WT1,
                                              unsigned short* __restrict__ WT2,
                                              int* __restrict__ cursor,
                                              float* __restrict__ pooled) {
    int idx = blockIdx.x * 256 + threadIdx.x;
    if (idx < TOTDEG) cursor[idx] = 0;
    if (idx < GPOOL * 128) pooled[idx] = 0.f;
    if (idx < 128 * 64) {
        int col = idx / 64, k = idx - col * 64;
        WT0[idx] = f2bf(W0[k * 128 + col]);
    }
    if (idx < 128 * 128) {
        int col = idx >> 7, k = idx & 127;
        WT1[idx] = f2bf(W1[k * 128 + col]);
        WT2[idx] = f2bf(W2[k * 128 + col]);
    }
}

// ---------------------------------------------------------------- CSR build
__global__ __launch_bounds__(256) void k_count_all(EiPtrs eis, int* __restrict__ deg) {
    int r = blockIdx.y;
    int e = blockIdx.x * 256 + threadIdx.x;
    if (e >= E_EDGES) return;
    int seg = seg_of(r, eis.p[r][E_EDGES + e]);
    int lo = blockIdx.z * SPP_C;
    if (seg < lo || seg >= lo + SPP_C) return;
    atomicAdd(&deg[seg], 1);
}

__global__ __launch_bounds__(256) void k_scan_partial(const int* __restrict__ deg,
                                                      int* __restrict__ bsum) {
    int t = threadIdx.x, b = blockIdx.x;
    int base = b * 1024 + t * 4;
    int sv = 0;
#pragma unroll
    for (int i = 0; i < 4; i++) {
        int idx = base + i;
        if (idx < TOTDEG) sv += deg[idx];
    }
#pragma unroll
    for (int msk = 1; msk < 64; msk <<= 1) sv += __shfl_xor(sv, msk);
    __shared__ int ws[4];
    if ((t & 63) == 0) ws[t >> 6] = sv;
    __syncthreads();
    if (t == 0) bsum[b] = ws[0] + ws[1] + ws[2] + ws[3];
}

__global__ __launch_bounds__(1024) void k_scan_bsums(int* __restrict__ bsum, int nb) {
    __shared__ int lds[1024];
    int t = threadIdx.x;
    int v = (t < nb) ? bsum[t] : 0;
    lds[t] = v;
    __syncthreads();
    for (int dd = 1; dd < 1024; dd <<= 1) {
        int u = (t >= dd) ? lds[t - dd] : 0;
        __syncthreads();
        lds[t] += u;
        __syncthreads();
    }
    if (t < nb) bsum[t] = lds[t] - v;  // exclusive
}

// writes offs AND cursor (cursor = fill's atomic start positions)
__global__ __launch_bounds__(256) void k_scan_final(const int* __restrict__ deg,
                                                    const int* __restrict__ bsum,
                                                    int* __restrict__ offs,
                                                    int* __restrict__ cursor) {
    int t = threadIdx.x, b = blockIdx.x;
    int base = b * 1024 + t * 4;
    int v[4];
    int tot = 0;
#pragma unroll
    for (int i = 0; i < 4; i++) {
        int idx = base + i;
        v[i] = (idx < TOTDEG) ? deg[idx] : 0;
        tot += v[i];
    }
    int lane = t & 63, w = t >> 6;
    int x = tot;
#pragma unroll
    for (int dd = 1; dd < 64; dd <<= 1) {
        int u = __shfl_up(x, dd);
        if (lane >= dd) x += u;
    }
    __shared__ int wt[4];
    if (lane == 63) wt[w] = x;
    __syncthreads();
    int wbase = 0;
#pragma unroll
    for (int j = 0; j < 4; j++)
        if (j < w) wbase += wt[j];
    int run = bsum[b] + wbase + (x - tot);
#pragma unroll
    for (int i = 0; i < 4; i++) {
        int idx = base + i;
        if (idx <= TOTDEG) offs[idx] = run;
        if (idx < TOTDEG) cursor[idx] = run;
        run += v[i];
    }
}

__global__ __launch_bounds__(256) void k_fill_all(EiPtrs eis, int* __restrict__ cursor,
                                                  int* __restrict__ list) {
    int r = blockIdx.y;
    int e = blockIdx.x * 256 + threadIdx.x;
    if (e >= E_EDGES) return;
    const int* ei = eis.p[r];
    int seg = seg_of(r, ei[E_EDGES + e]);
    int lo = blockIdx.z * SPP_F;
    if (seg < lo || seg >= lo + SPP_F) return;
    int pos = atomicAdd(&cursor[seg], 1);
    list[pos] = ei[e] + srcbase_of(r);  // global src id
}

// ---------------------------------------------------------------- MFMA GEMM body
template <int K, bool BF16IN>
__device__ __forceinline__ void gemm_body(const void* __restrict__ xv,
                                          const unsigned short* __restrict__ WT,
                                          const float* __restrict__ avs,
                                          const float* __restrict__ avd,
                                          unsigned short* __restrict__ h,
                                          float* __restrict__ s, float* __restrict__ d,
                                          int N, int row0) {
    constexpr int NQ = K / 32;
    __shared__ float csmem[64][130];  // aliased: WT tile first, C tile after
    char* sw = (char*)&csmem[0][0];
    int tid = threadIdx.x;
    int w = tid >> 6, l = tid & 63;

    constexpr int WT_BYTES = 128 * K * 2;
#pragma unroll
    for (int i = tid * 16; i < WT_BYTES; i += 256 * 16) {
        uint4 v = *(const uint4*)((const char*)WT + i);
        int row = i / (2 * K);
        int addr = i ^ ((row & 7) << 4);
        *(uint4*)(sw + addr) = v;
    }

    int arow = row0 + w * 16 + (l & 15);
    bf16x8 afrag[NQ];
    if (arow < N) {
        if (BF16IN) {
            const unsigned short* x = (const unsigned short*)xv;
#pragma unroll
            for (int q = 0; q < NQ; ++q) {
                int kc = q * 32 + (l >> 4) * 8;
                afrag[q] = *(const bf16x8*)&x[(size_t)arow * K + kc];
            }
        } else {
            const float* x = (const float*)xv;
#pragma unroll
            for (int q = 0; q < NQ; ++q) {
                int kc = q * 32 + (l >> 4) * 8;
                float4 f0 = *(const float4*)&x[(size_t)arow * K + kc];
                float4 f1 = *(const float4*)&x[(size_t)arow * K + kc + 4];
                bf16x8 a;
                a[0] = (short)f2bf(f0.x);
                a[1] = (short)f2bf(f0.y);
                a[2] = (short)f2bf(f0.z);
                a[3] = (short)f2bf(f0.w);
                a[4] = (short)f2bf(f1.x);
                a[5] = (short)f2bf(f1.y);
                a[6] = (short)f2bf(f1.z);
                a[7] = (short)f2bf(f1.w);
                afrag[q] = a;
            }
        }
    } else {
#pragma unroll
        for (int q = 0; q < NQ; ++q) {
            bf16x8 z = {0, 0, 0, 0, 0, 0, 0, 0};
            afrag[q] = z;
        }
    }
    __syncthreads();

    f32x4 acc[8];
#pragma unroll
    for (int c = 0; c < 8; ++c) acc[c] = (f32x4){0.f, 0.f, 0.f, 0.f};

#pragma unroll
    for (int c = 0; c < 8; ++c) {
        int cabs = c * 16 + (l & 15);
        int base = cabs * (2 * K) + ((l >> 4) * 16);
        int swz = (cabs & 7) << 4;
#pragma unroll
        for (int q = 0; q < NQ; ++q) {
            int addr = (base + q * 64) ^ swz;
            bf16x8 b = *(const bf16x8*)(sw + addr);
            acc[c] = __builtin_amdgcn_mfma_f32_16x16x32_bf16(afrag[q], b, acc[c], 0, 0, 0);
        }
    }
    __syncthreads();  // all waves done reading WT; reuse LDS for C

    int crow = w * 16 + (l >> 4) * 4;
    int ccol = l & 15;
#pragma unroll
    for (int c = 0; c < 8; ++c)
#pragma unroll
        for (int r = 0; r < 4; ++r) csmem[crow + r][c * 16 + ccol] = acc[c][r];
    __syncthreads();

    int row = tid >> 2, cg = tid & 3;
    int grow = row0 + row;
    if (grow < N) {
        float sv = 0.f, dv = 0.f;
        unsigned short tmp[32];
#pragma unroll
        for (int i = 0; i < 32; ++i) {
            float v = csmem[row][cg * 32 + i];
            sv = fmaf(v, avs[cg * 32 + i], sv);
            dv = fmaf(v, avd[cg * 32 + i], dv);
            tmp[i] = f2bf(v);
        }
        unsigned short* hp = &h[(size_t)grow * 128 + cg * 32];
        *(uint4*)&hp[0] = *(uint4*)&tmp[0];
        *(uint4*)&hp[8] = *(uint4*)&tmp[8];
        *(uint4*)&hp[16] = *(uint4*)&tmp[16];
        *(uint4*)&hp[24] = *(uint4*)&tmp[24];
        sv += __shfl_xor(sv, 1);
        sv += __shfl_xor(sv, 2);
        dv += __shfl_xor(dv, 1);
        dv += __shfl_xor(dv, 2);
        if (cg == 0) {
            s[grow] = sv;
            d[grow] = dv;
        }
    }
}

// L0: all 3 node types in one dispatch (grid.y = type)
__global__ __launch_bounds__(256) void gemm_l0(const float* __restrict__ xp,
                                               const float* __restrict__ xf,
                                               const float* __restrict__ xpo,
                                               const unsigned short* __restrict__ WT,
                                               const float* __restrict__ avs,
                                               const float* __restrict__ avd,
                                               unsigned short* __restrict__ H,
                                               float* __restrict__ s_all,
                                               float* __restrict__ d_all) {
    int ty = blockIdx.y;
    const float* x;
    int N, rowoff;
    if (ty == 0) {
        x = xp;
        N = NP;
        rowoff = 0;
    } else if (ty == 1) {
        x = xf;
        N = NF;
        rowoff = NP;
    } else {
        x = xpo;
        N = NPORT;
        rowoff = NP + NF;
    }
    int row0 = blockIdx.x * 64;
    if (row0 >= N) return;
    gemm_body<64, false>(x, WT, avs, avd, H + (size_t)rowoff * 128, s_all + rowoff,
                         d_all + rowoff, N, row0);
}

__global__ __launch_bounds__(256) void gemm_big(const unsigned short* __restrict__ X,
                                                const unsigned short* __restrict__ WT,
                                                const float* __restrict__ avs,
                                                const float* __restrict__ avd,
                                                unsigned short* __restrict__ H,
                                                float* __restrict__ s_all,
                                                float* __restrict__ d_all) {
    gemm_body<128, true>(X, WT, avs, avd, H, s_all, d_all, NTOT, blockIdx.x * 64);
}

// ---------------------------------------------------------------- edge weights
// one thread per segment (850k): online softmax, write normalized bf16 weights
__global__ __launch_bounds__(256) void k_edgew(const int* __restrict__ offs,
                                               const int* __restrict__ list,
                                               const float* __restrict__ s_all,
                                               const float* __restrict__ d_all,
                                               unsigned short* __restrict__ wE) {
    int seg = blockIdx.x * 256 + threadIdx.x;
    if (seg >= TOTDEG) return;
    int o0 = offs[seg], o1 = offs[seg + 1];
    if (o1 == o0) return;
    int dst_g;
    if (seg < 500000)
        dst_g = seg / 5;
    else if (seg < 700000)
        dst_g = 100000 + (seg - 500000) / 2;
    else
        dst_g = 200000 + (seg - 700000) / 3;
    float dd = d_all[dst_g];
    float m = -1e30f, den = 0.f;
    for (int j = o0; j < o1; ++j) {
        float x = s_all[list[j]] + dd;
        x = (x >= 0.f) ? x : 0.2f * x;
        if (x > m) {
            den = den * __expf(m - x) + 1.f;
            m = x;
        } else {
            den += __expf(x - m);
        }
    }
    float invden = 1.f / fmaxf(den, 1e-16f);
    for (int j = o0; j < o1; ++j) {
        float x = s_all[list[j]] + dd;
        x = (x >= 0.f) ? x : 0.2f * x;
        wE[j] = f2bf(__expf(x - m) * invden);
    }
}

// ---------------------------------------------------------------- gather
// R5/R8 measured-best: 32-lane group per dst; even/odd 16-lane halves with
// ushort8 (16B) slices -> 2 edges concurrent, unroll x2 -> 4 rows in flight.
__global__ __launch_bounds__(256) void k_gather(const int* __restrict__ offs,
                                                const int* __restrict__ list,
                                                const unsigned short* __restrict__ wE,
                                                const float* __restrict__ bias,
                                                const unsigned short* __restrict__ H,
                                                unsigned short* __restrict__ X) {
    int grp = threadIdx.x >> 5, lane = threadIdx.x & 31;
    int dst = blockIdx.x * 8 + grp;
    if (dst >= NTOT) return;
    int seg0, nrel;
    float inv;
    if (dst < 100000) {
        seg0 = dst * 5;
        nrel = 5;
        inv = 0.2f;
    } else if (dst < 200000) {
        seg0 = 500000 + (dst - 100000) * 2;
        nrel = 2;
        inv = 0.5f;
    } else {
        seg0 = 700000 + (dst - 200000) * 3;
        nrel = 3;
        inv = 1.f / 3.f;
    }
    int o0 = offs[seg0], o1 = offs[seg0 + nrel];
    int half = lane >> 4;  // 0: even edges, 1: odd edges
    int l16 = lane & 15;
    float a[8] = {0.f, 0.f, 0.f, 0.f, 0.f, 0.f, 0.f, 0.f};
    float b[8] = {0.f, 0.f, 0.f, 0.f, 0.f, 0.f, 0.f, 0.f};
    int j = o0 + half;
    for (; j + 2 < o1; j += 4) {
        int s0 = list[j], s1 = list[j + 2];
        float w0 = bf2f(wE[j]), w1 = bf2f(wE[j + 2]);
        uint4 r0 = *(const uint4*)&H[(size_t)s0 * 128 + l16 * 8];
        uint4 r1 = *(const uint4*)&H[(size_t)s1 * 128 + l16 * 8];
        const unsigned short* u0 = (const unsigned short*)&r0;
        const unsigned short* u1 = (const unsigned short*)&r1;
#pragma unroll
        for (int k = 0; k < 8; ++k) a[k] = fmaf(w0, bf2f(u0[k]), a[k]);
#pragma unroll
        for (int k = 0; k < 8; ++k) b[k] = fmaf(w1, bf2f(u1[k]), b[k]);
    }
    for (; j < o1; j += 2) {
        int s0 = list[j];
        float w0 = bf2f(wE[j]);
        uint4 r0 = *(const uint4*)&H[(size_t)s0 * 128 + l16 * 8];
        const unsigned short* u0 = (const unsigned short*)&r0;
#pragma unroll
        for (int k = 0; k < 8; ++k) a[k] = fmaf(w0, bf2f(u0[k]), a[k]);
    }
#pragma unroll
    for (int k = 0; k < 8; ++k) {
        a[k] += b[k];
        a[k] += __shfl_xor(a[k], 16);
    }
    // half0 stores cols l16*8..+3 (a[0..3]); half1 stores l16*8+4..+7 (a[4..7])
    int c0 = l16 * 8 + half * 4;
    float4 b4 = *(const float4*)&bias[c0];
    float v0 = fmaf(a[half * 4 + 0], inv, b4.x);
    float v1 = fmaf(a[half * 4 + 1], inv, b4.y);
    float v2 = fmaf(a[half * 4 + 2], inv, b4.z);
    float v3 = fmaf(a[half * 4 + 3], inv, b4.w);
    v0 = (v0 >= 0.f) ? v0 : 0.01f * v0;
    v1 = (v1 >= 0.f) ? v1 : 0.01f * v1;
    v2 = (v2 >= 0.f) ? v2 : 0.01f * v2;
    v3 = (v3 >= 0.f) ? v3 : 0.01f * v3;
    ushort4 o;
    o.x = f2bf(v0);
    o.y = f2bf(v1);
    o.z = f2bf(v2);
    o.w = f2bf(v3);
    *(ushort4*)&X[(size_t)dst * 128 + c0] = o;
}

// ---------------------------------------------------------------- pooling (all types)
__global__ __launch_bounds__(128) void pool_all(const unsigned short* __restrict__ X,
                                                const int* __restrict__ bp,
                                                const int* __restrict__ bf,
                                                const int* __restrict__ bpo,
                                                float* __restrict__ pooled) {
    int t = threadIdx.x;
    int start = blockIdx.x * 128;
    int end = min(start + 128, NTOT);
    if (start >= end) return;
    auto bat = [&](int i) {
        return (i < NP) ? bp[i] : (i < NP + NF) ? bf[i - NP] : bpo[i - NP - NF];
    };
    float acc = 0.f;
    int g = bat(start);
    for (int i = start; i < end; ++i) {
        int gi = bat(i);
        if (gi != g) {
            atomicAdd(&pooled[(size_t)g * 128 + t], acc);
            acc = 0.f;
            g = gi;
        }
        acc += bf2f(X[(size_t)i * 128 + t]);
    }
    atomicAdd(&pooled[(size_t)g * 128 + t], acc);
}

// ---------------------------------------------------------------- final MLP
__global__ __launch_bounds__(128) void k_mlp(const float* __restrict__ pooled,
                                             const float* __restrict__ w1,
                                             const float* __restrict__ b1,
                                             const float* __restrict__ w2,
                                             const float* __restrict__ b2,
                                             float* __restrict__ out) {
    __shared__ float p[128];
    __shared__ float r0[2], r1[2];
    int g = blockIdx.x, t = threadIdx.x;
    p[t] = pooled[g * 128 + t];
    __syncthreads();
    float acc = b1[t];
    for (int k = 0; k < 128; ++k) acc = fmaf(p[k], w1[k * 128 + t], acc);
    float v0 = acc * w2[t * 2 + 0];
    float v1 = acc * w2[t * 2 + 1];
#pragma unroll
    for (int msk = 1; msk < 64; msk <<= 1) {
        v0 += __shfl_xor(v0, msk);
        v1 += __shfl_xor(v1, msk);
    }
    if ((t & 63) == 0) {
        r0[t >> 6] = v0;
        r1[t >> 6] = v1;
    }
    __syncthreads();
    if (t == 0) {
        out[g * 2 + 0] = r0[0] + r0[1] + b2[0];
        out[g * 2 + 1] = r1[0] + r1[1] + b2[1];
    }
}

// workspace-too-small diagnostic: report ws_size via the absmax channel
__global__ void k_ws_debug(float* out, int n, float val) {
    int i = blockIdx.x * 256 + threadIdx.x;
    if (i < n) out[i] = val;
}

// ---------------------------------------------------------------- launch
extern "C" void kernel_launch(void* const* d_in, const int* in_sizes, int n_in,
                              void* d_out, int out_size, void* d_ws, size_t ws_size,
                              hipStream_t stream) {
    const float* x_p0 = (const float*)d_in[0];
    const float* x_f0 = (const float*)d_in[1];
    const float* x_po0 = (const float*)d_in[2];
    const float* Wl[3] = {(const float*)d_in[3], (const float*)d_in[7],
                          (const float*)d_in[11]};
    const float* asl[3] = {(const float*)d_in[4], (const float*)d_in[8],
                           (const float*)d_in[12]};
    const float* adl[3] = {(const float*)d_in[5], (const float*)d_in[9],
                           (const float*)d_in[13]};
    const float* bl[3] = {(const float*)d_in[6], (const float*)d_in[10],
                          (const float*)d_in[14]};
    const float* lin1_w = (const float*)d_in[15];
    const float* lin1_b = (const float*)d_in[16];
    const float* lin2_w = (const float*)d_in[17];
    const float* lin2_b = (const float*)d_in[18];
    // relation order: 0..4 dst=process, 5..6 dst=file, 7..9 dst=port
    EiPtrs eis;
    eis.p[0] = (const int*)d_in[20];  // rev_access  (file -> proc)
    eis.p[1] = (const int*)d_in[22];  // rev_same_as (file -> proc)
    eis.p[2] = (const int*)d_in[24];  // rev_bind    (port -> proc)
    eis.p[3] = (const int*)d_in[27];  // create      (proc -> proc)
    eis.p[4] = (const int*)d_in[28];  // rev_create  (proc -> proc)
    eis.p[5] = (const int*)d_in[19];  // access      (proc -> file)
    eis.p[6] = (const int*)d_in[21];  // same_as     (proc -> file)
    eis.p[7] = (const int*)d_in[23];  // bind        (proc -> port)
    eis.p[8] = (const int*)d_in[25];  // session     (port -> port)
    eis.p[9] = (const int*)d_in[26];  // rev_session (port -> port)
    const int* batch_p = (const int*)d_in[29];
    const int* batch_f = (const int*)d_in[30];
    const int* batch_po = (const int*)d_in[31];
    float* out = (float*)d_out;

    // workspace layout (16B aligned)
    char* w = (char*)d_ws;
    size_t off = 0;
    int* offs = (int*)(w + off);      off += (size_t)850004 * 4;
    int* cursor = (int*)(w + off);    off += (size_t)TOTDEG * 4;
    int* list = (int*)(w + off);      off += (size_t)10 * E_EDGES * 4;
    int* bsum = (int*)(w + off);      off += 4096;
    unsigned short* H = (unsigned short*)(w + off); off += (size_t)NTOT * 128 * 2;
    unsigned short* X = (unsigned short*)(w + off); off += (size_t)NTOT * 128 * 2;
    float* s_all = (float*)(w + off); off += (size_t)NTOT * 4;
    float* d_all = (float*)(w + off); off += (size_t)NTOT * 4;
    float* pooled = (float*)(w + off); off += (size_t)GPOOL * 128 * 4;
    unsigned short* WT0 = (unsigned short*)(w + off); off += (size_t)128 * 64 * 2;
    unsigned short* WT1 = (unsigned short*)(w + off); off += (size_t)128 * 128 * 2;
    unsigned short* WT2 = (unsigned short*)(w + off); off += (size_t)128 * 128 * 2;
    unsigned short* wE = (unsigned short*)(w + off); off += (size_t)10 * E_EDGES * 2;
    if (ws_size < off) {
        k_ws_debug<<<(out_size + 255) / 256, 256, 0, stream>>>(out, out_size,
                                                               (float)ws_size);
        return;
    }

    k_init<<<(TOTDEG + 255) / 256, 256, 0, stream>>>(Wl[0], Wl[1], Wl[2], WT0, WT1, WT2,
                                                     cursor, pooled);

    int eb = (E_EDGES + 255) / 256;
    k_count_all<<<dim3(eb, 10, NPART_C), 256, 0, stream>>>(eis, cursor);
    int nb = (TOTDEG + 1 + 1023) / 1024;  // 831
    k_scan_partial<<<nb, 256, 0, stream>>>(cursor, bsum);
    k_scan_bsums<<<1, 1024, 0, stream>>>(bsum, nb);
    k_scan_final<<<nb, 256, 0, stream>>>(cursor, bsum, offs, cursor);
    k_fill_all<<<dim3(eb, 10, NPART_F), 256, 0, stream>>>(eis, cursor, list);

    for (int L = 0; L < 3; ++L) {
        if (L == 0) {
            gemm_l0<<<dim3((NP + 63) / 64, 3), 256, 0, stream>>>(
                x_p0, x_f0, x_po0, WT0, asl[0], adl[0], H, s_all, d_all);
        } else {
            const unsigned short* WTL = (L == 1) ? WT1 : WT2;
            gemm_big<<<(NTOT + 63) / 64, 256, 0, stream>>>(X, WTL, asl[L], adl[L], H,
                                                           s_all, d_all);
        }
        k_edgew<<<(TOTDEG + 255) / 256, 256, 0, stream>>>(offs, list, s_all, d_all, wE);
        k_gather<<<(NTOT + 7) / 8, 256, 0, stream>>>(offs, list, wE, bl[L], H, X);
    }

    pool_all<<<(NTOT + 127) / 128, 128, 0, stream>>>(X, batch_p, batch_f, batch_po,
                                                     pooled);

    k_mlp<<<GPOOL, 128, 0, stream>>>(pooled, lin1_w, lin1_b, lin2_w, lin2_b, out);
}

// Round 11
// 827.695 us; speedup vs baseline: 1.3880x; 1.0407x over previous
//
#include <hip/hip_runtime.h>
#include <cstdint>
#include <cstddef>

#define E_EDGES 200000
#define NP 100000
#define NF 100000
#define NPORT 50000
#define NTOT 250000
#define TOTDEG 850000
#define GPOOL 128
#define NPART_C 8
#define SPP_C 106250
#define NPART_F 8
#define SPP_F 106250

typedef __attribute__((ext_vector_type(8))) short bf16x8;
typedef __attribute__((ext_vector_type(4))) float f32x4;

__device__ __forceinline__ float bf2f(unsigned short u) {
    return __uint_as_float(((unsigned int)u) << 16);
}
__device__ __forceinline__ unsigned short f2bf(float f) {
    unsigned int x = __float_as_uint(f);
    return (unsigned short)((x + 0x7fffu + ((x >> 16) & 1u)) >> 16);
}

struct EiPtrs {
    const int* p[10];
};

// seg layout (dst-major): proc dst v: segs 5v+r; file: 500000+2v+r; port: 700000+3v+r.
// list[] stores GLOBAL src id (proc +0, file +100000, port +200000).
__device__ __forceinline__ int seg_of(int r, int dst) {
    if (r < 5) return dst * 5 + r;
    if (r < 7) return 500000 + dst * 2 + (r - 5);
    return 700000 + dst * 3 + (r - 7);
}
__device__ __forceinline__ int srcbase_of(int r) {
    return (r <= 1) ? 100000 : (r == 2 || r >= 8) ? 200000 : 0;
}

// ---------------------------------------------------------------- init (fused)
__global__ __launch_bounds__(256) void k_init(const float* __restrict__ W0,
                                              const float* __restrict__ W1,
                                              const float* __restrict__ W2,
                                              unsigned short* __restrict__ WT0,
                                              unsigned short* __restrict__ WT1,
                                              unsigned short* __restrict__ WT2,
                                              int* __restrict__ cursor,
                                              float* __restrict__ pooled) {
    int idx = blockIdx.x * 256 + threadIdx.x;
    if (idx < TOTDEG) cursor[idx] = 0;
    if (idx < GPOOL * 128) pooled[idx] = 0.f;
    if (idx < 128 * 64) {
        int col = idx / 64, k = idx - col * 64;
        WT0[idx] = f2bf(W0[k * 128 + col]);
    }
    if (idx < 128 * 128) {
        int col = idx >> 7, k = idx & 127;
        WT1[idx] = f2bf(W1[k * 128 + col]);
        WT2[idx] = f2bf(W2[k * 128 + col]);
    }
}

// ---------------------------------------------------------------- CSR build
// z-partitioned (proven at 8): only commit segs in this z-slice so the
// atomic/write window stays L2-resident and stores merge before write-back.
__global__ __launch_bounds__(256) void k_count_all(EiPtrs eis, int* __restrict__ deg) {
    int r = blockIdx.y;
    int e = blockIdx.x * 256 + threadIdx.x;
    if (e >= E_EDGES) return;
    int seg = seg_of(r, eis.p[r][E_EDGES + e]);
    int lo = blockIdx.z * SPP_C;
    if (seg < lo || seg >= lo + SPP_C) return;
    atomicAdd(&deg[seg], 1);
}

__global__ __launch_bounds__(256) void k_scan_partial(const int* __restrict__ deg,
                                                      int* __restrict__ bsum) {
    int t = threadIdx.x, b = blockIdx.x;
    int base = b * 1024 + t * 4;
    int sv = 0;
#pragma unroll
    for (int i = 0; i < 4; i++) {
        int idx = base + i;
        if (idx < TOTDEG) sv += deg[idx];
    }
#pragma unroll
    for (int msk = 1; msk < 64; msk <<= 1) sv += __shfl_xor(sv, msk);
    __shared__ int ws[4];
    if ((t & 63) == 0) ws[t >> 6] = sv;
    __syncthreads();
    if (t == 0) bsum[b] = ws[0] + ws[1] + ws[2] + ws[3];
}

__global__ __launch_bounds__(1024) void k_scan_bsums(int* __restrict__ bsum, int nb) {
    __shared__ int lds[1024];
    int t = threadIdx.x;
    int v = (t < nb) ? bsum[t] : 0;
    lds[t] = v;
    __syncthreads();
    for (int dd = 1; dd < 1024; dd <<= 1) {
        int u = (t >= dd) ? lds[t - dd] : 0;
        __syncthreads();
        lds[t] += u;
        __syncthreads();
    }
    if (t < nb) bsum[t] = lds[t] - v;  // exclusive
}

// writes offs AND cursor (cursor = fill's atomic start positions)
__global__ __launch_bounds__(256) void k_scan_final(const int* __restrict__ deg,
                                                    const int* __restrict__ bsum,
                                                    int* __restrict__ offs,
                                                    int* __restrict__ cursor) {
    int t = threadIdx.x, b = blockIdx.x;
    int base = b * 1024 + t * 4;
    int v[4];
    int tot = 0;
#pragma unroll
    for (int i = 0; i < 4; i++) {
        int idx = base + i;
        v[i] = (idx < TOTDEG) ? deg[idx] : 0;
        tot += v[i];
    }
    int lane = t & 63, w = t >> 6;
    int x = tot;
#pragma unroll
    for (int dd = 1; dd < 64; dd <<= 1) {
        int u = __shfl_up(x, dd);
        if (lane >= dd) x += u;
    }
    __shared__ int wt[4];
    if (lane == 63) wt[w] = x;
    __syncthreads();
    int wbase = 0;
#pragma unroll
    for (int j = 0; j < 4; j++)
        if (j < w) wbase += wt[j];
    int run = bsum[b] + wbase + (x - tot);
#pragma unroll
    for (int i = 0; i < 4; i++) {
        int idx = base + i;
        if (idx <= TOTDEG) offs[idx] = run;
        if (idx < TOTDEG) cursor[idx] = run;
        run += v[i];
    }
}

__global__ __launch_bounds__(256) void k_fill_all(EiPtrs eis, int* __restrict__ cursor,
                                                  int* __restrict__ list) {
    int r = blockIdx.y;
    int e = blockIdx.x * 256 + threadIdx.x;
    if (e >= E_EDGES) return;
    const int* ei = eis.p[r];
    int seg = seg_of(r, ei[E_EDGES + e]);
    int lo = blockIdx.z * SPP_F;
    if (seg < lo || seg >= lo + SPP_F) return;
    int pos = atomicAdd(&cursor[seg], 1);
    list[pos] = ei[e] + srcbase_of(r);  // global src id
}

// ---------------------------------------------------------------- MFMA GEMM body
template <int K, bool BF16IN>
__device__ __forceinline__ void gemm_body(const void* __restrict__ xv,
                                          const unsigned short* __restrict__ WT,
                                          const float* __restrict__ avs,
                                          const float* __restrict__ avd,
                                          unsigned short* __restrict__ h,
                                          float* __restrict__ s, float* __restrict__ d,
                                          int N, int row0) {
    constexpr int NQ = K / 32;
    __shared__ float csmem[64][130];  // aliased: WT tile first, C tile after
    char* sw = (char*)&csmem[0][0];
    int tid = threadIdx.x;
    int w = tid >> 6, l = tid & 63;

    constexpr int WT_BYTES = 128 * K * 2;
#pragma unroll
    for (int i = tid * 16; i < WT_BYTES; i += 256 * 16) {
        uint4 v = *(const uint4*)((const char*)WT + i);
        int row = i / (2 * K);
        int addr = i ^ ((row & 7) << 4);
        *(uint4*)(sw + addr) = v;
    }

    int arow = row0 + w * 16 + (l & 15);
    bf16x8 afrag[NQ];
    if (arow < N) {
        if (BF16IN) {
            const unsigned short* x = (const unsigned short*)xv;
#pragma unroll
            for (int q = 0; q < NQ; ++q) {
                int kc = q * 32 + (l >> 4) * 8;
                afrag[q] = *(const bf16x8*)&x[(size_t)arow * K + kc];
            }
        } else {
            const float* x = (const float*)xv;
#pragma unroll
            for (int q = 0; q < NQ; ++q) {
                int kc = q * 32 + (l >> 4) * 8;
                float4 f0 = *(const float4*)&x[(size_t)arow * K + kc];
                float4 f1 = *(const float4*)&x[(size_t)arow * K + kc + 4];
                bf16x8 a;
                a[0] = (short)f2bf(f0.x);
                a[1] = (short)f2bf(f0.y);
                a[2] = (short)f2bf(f0.z);
                a[3] = (short)f2bf(f0.w);
                a[4] = (short)f2bf(f1.x);
                a[5] = (short)f2bf(f1.y);
                a[6] = (short)f2bf(f1.z);
                a[7] = (short)f2bf(f1.w);
                afrag[q] = a;
            }
        }
    } else {
#pragma unroll
        for (int q = 0; q < NQ; ++q) {
            bf16x8 z = {0, 0, 0, 0, 0, 0, 0, 0};
            afrag[q] = z;
        }
    }
    __syncthreads();

    f32x4 acc[8];
#pragma unroll
    for (int c = 0; c < 8; ++c) acc[c] = (f32x4){0.f, 0.f, 0.f, 0.f};

#pragma unroll
    for (int c = 0; c < 8; ++c) {
        int cabs = c * 16 + (l & 15);
        int base = cabs * (2 * K) + ((l >> 4) * 16);
        int swz = (cabs & 7) << 4;
#pragma unroll
        for (int q = 0; q < NQ; ++q) {
            int addr = (base + q * 64) ^ swz;
            bf16x8 b = *(const bf16x8*)(sw + addr);
            acc[c] = __builtin_amdgcn_mfma_f32_16x16x32_bf16(afrag[q], b, acc[c], 0, 0, 0);
        }
    }
    __syncthreads();  // all waves done reading WT; reuse LDS for C

    int crow = w * 16 + (l >> 4) * 4;
    int ccol = l & 15;
#pragma unroll
    for (int c = 0; c < 8; ++c)
#pragma unroll
        for (int r = 0; r < 4; ++r) csmem[crow + r][c * 16 + ccol] = acc[c][r];
    __syncthreads();

    int row = tid >> 2, cg = tid & 3;
    int grow = row0 + row;
    if (grow < N) {
        float sv = 0.f, dv = 0.f;
        unsigned short tmp[32];
#pragma unroll
        for (int i = 0; i < 32; ++i) {
            float v = csmem[row][cg * 32 + i];
            sv = fmaf(v, avs[cg * 32 + i], sv);
            dv = fmaf(v, avd[cg * 32 + i], dv);
            tmp[i] = f2bf(v);
        }
        unsigned short* hp = &h[(size_t)grow * 128 + cg * 32];
        *(uint4*)&hp[0] = *(uint4*)&tmp[0];
        *(uint4*)&hp[8] = *(uint4*)&tmp[8];
        *(uint4*)&hp[16] = *(uint4*)&tmp[16];
        *(uint4*)&hp[24] = *(uint4*)&tmp[24];
        sv += __shfl_xor(sv, 1);
        sv += __shfl_xor(sv, 2);
        dv += __shfl_xor(dv, 1);
        dv += __shfl_xor(dv, 2);
        if (cg == 0) {
            s[grow] = sv;
            d[grow] = dv;
        }
    }
}

// L0: all 3 node types in one dispatch (grid.y = type)
__global__ __launch_bounds__(256) void gemm_l0(const float* __restrict__ xp,
                                               const float* __restrict__ xf,
                                               const float* __restrict__ xpo,
                                               const unsigned short* __restrict__ WT,
                                               const float* __restrict__ avs,
                                               const float* __restrict__ avd,
                                               unsigned short* __restrict__ H,
                                               float* __restrict__ s_all,
                                               float* __restrict__ d_all) {
    int ty = blockIdx.y;
    const float* x;
    int N, rowoff;
    if (ty == 0) {
        x = xp;
        N = NP;
        rowoff = 0;
    } else if (ty == 1) {
        x = xf;
        N = NF;
        rowoff = NP;
    } else {
        x = xpo;
        N = NPORT;
        rowoff = NP + NF;
    }
    int row0 = blockIdx.x * 64;
    if (row0 >= N) return;
    gemm_body<64, false>(x, WT, avs, avd, H + (size_t)rowoff * 128, s_all + rowoff,
                         d_all + rowoff, N, row0);
}

__global__ __launch_bounds__(256) void gemm_big(const unsigned short* __restrict__ X,
                                                const unsigned short* __restrict__ WT,
                                                const float* __restrict__ avs,
                                                const float* __restrict__ avd,
                                                unsigned short* __restrict__ H,
                                                float* __restrict__ s_all,
                                                float* __restrict__ d_all) {
    gemm_body<128, true>(X, WT, avs, avd, H, s_all, d_all, NTOT, blockIdx.x * 64);
}

// ---------------------------------------------------------------- edge weights
// one thread per segment (850k). Pass 1: gather s_all once, cache leaky-x as
// bf16 in wE (sequential), online max/den on the bf16-rounded value. Pass 2:
// re-read wE sequentially, write normalized weight. Halves random gathers.
__global__ __launch_bounds__(256) void k_edgew(const int* __restrict__ offs,
                                               const int* __restrict__ list,
                                               const float* __restrict__ s_all,
                                               const float* __restrict__ d_all,
                                               unsigned short* __restrict__ wE) {
    int seg = blockIdx.x * 256 + threadIdx.x;
    if (seg >= TOTDEG) return;
    int o0 = offs[seg], o1 = offs[seg + 1];
    if (o1 == o0) return;
    int dst_g;
    if (seg < 500000)
        dst_g = seg / 5;
    else if (seg < 700000)
        dst_g = 100000 + (seg - 500000) / 2;
    else
        dst_g = 200000 + (seg - 700000) / 3;
    float dd = d_all[dst_g];
    float m = -1e30f, den = 0.f;
    for (int j = o0; j < o1; ++j) {
        float x = s_all[list[j]] + dd;
        x = (x >= 0.f) ? x : 0.2f * x;
        unsigned short xb = f2bf(x);
        wE[j] = xb;           // cache rounded x
        x = bf2f(xb);         // use the SAME rounded value for m/den
        if (x > m) {
            den = den * __expf(m - x) + 1.f;
            m = x;
        } else {
            den += __expf(x - m);
        }
    }
    float invden = 1.f / fmaxf(den, 1e-16f);
    for (int j = o0; j < o1; ++j) {
        float x = bf2f(wE[j]);
        wE[j] = f2bf(__expf(x - m) * invden);
    }
}

// ---------------------------------------------------------------- gather
// R5/R8 measured-best: 32-lane group per dst; even/odd 16-lane halves with
// ushort8 (16B) slices -> 2 edges concurrent, unroll x2 -> 4 rows in flight.
__global__ __launch_bounds__(256) void k_gather(const int* __restrict__ offs,
                                                const int* __restrict__ list,
                                                const unsigned short* __restrict__ wE,
                                                const float* __restrict__ bias,
                                                const unsigned short* __restrict__ H,
                                                unsigned short* __restrict__ X) {
    int grp = threadIdx.x >> 5, lane = threadIdx.x & 31;
    int dst = blockIdx.x * 8 + grp;
    if (dst >= NTOT) return;
    int seg0, nrel;
    float inv;
    if (dst < 100000) {
        seg0 = dst * 5;
        nrel = 5;
        inv = 0.2f;
    } else if (dst < 200000) {
        seg0 = 500000 + (dst - 100000) * 2;
        nrel = 2;
        inv = 0.5f;
    } else {
        seg0 = 700000 + (dst - 200000) * 3;
        nrel = 3;
        inv = 1.f / 3.f;
    }
    int o0 = offs[seg0], o1 = offs[seg0 + nrel];
    int half = lane >> 4;  // 0: even edges, 1: odd edges
    int l16 = lane & 15;
    float a[8] = {0.f, 0.f, 0.f, 0.f, 0.f, 0.f, 0.f, 0.f};
    float b[8] = {0.f, 0.f, 0.f, 0.f, 0.f, 0.f, 0.f, 0.f};
    int j = o0 + half;
    for (; j + 2 < o1; j += 4) {
        int s0 = list[j], s1 = list[j + 2];
        float w0 = bf2f(wE[j]), w1 = bf2f(wE[j + 2]);
        uint4 r0 = *(const uint4*)&H[(size_t)s0 * 128 + l16 * 8];
        uint4 r1 = *(const uint4*)&H[(size_t)s1 * 128 + l16 * 8];
        const unsigned short* u0 = (const unsigned short*)&r0;
        const unsigned short* u1 = (const unsigned short*)&r1;
#pragma unroll
        for (int k = 0; k < 8; ++k) a[k] = fmaf(w0, bf2f(u0[k]), a[k]);
#pragma unroll
        for (int k = 0; k < 8; ++k) b[k] = fmaf(w1, bf2f(u1[k]), b[k]);
    }
    for (; j < o1; j += 2) {
        int s0 = list[j];
        float w0 = bf2f(wE[j]);
        uint4 r0 = *(const uint4*)&H[(size_t)s0 * 128 + l16 * 8];
        const unsigned short* u0 = (const unsigned short*)&r0;
#pragma unroll
        for (int k = 0; k < 8; ++k) a[k] = fmaf(w0, bf2f(u0[k]), a[k]);
    }
#pragma unroll
    for (int k = 0; k < 8; ++k) {
        a[k] += b[k];
        a[k] += __shfl_xor(a[k], 16);
    }
    // half0 stores cols l16*8..+3 (a[0..3]); half1 stores l16*8+4..+7 (a[4..7])
    int c0 = l16 * 8 + half * 4;
    float4 b4 = *(const float4*)&bias[c0];
    float v0 = fmaf(a[half * 4 + 0], inv, b4.x);
    float v1 = fmaf(a[half * 4 + 1], inv, b4.y);
    float v2 = fmaf(a[half * 4 + 2], inv, b4.z);
    float v3 = fmaf(a[half * 4 + 3], inv, b4.w);
    v0 = (v0 >= 0.f) ? v0 : 0.01f * v0;
    v1 = (v1 >= 0.f) ? v1 : 0.01f * v1;
    v2 = (v2 >= 0.f) ? v2 : 0.01f * v2;
    v3 = (v3 >= 0.f) ? v3 : 0.01f * v3;
    ushort4 o;
    o.x = f2bf(v0);
    o.y = f2bf(v1);
    o.z = f2bf(v2);
    o.w = f2bf(v3);
    *(ushort4*)&X[(size_t)dst * 128 + c0] = o;
}

// ---------------------------------------------------------------- pooling (all types)
__global__ __launch_bounds__(128) void pool_all(const unsigned short* __restrict__ X,
                                                const int* __restrict__ bp,
                                                const int* __restrict__ bf,
                                                const int* __restrict__ bpo,
                                                float* __restrict__ pooled) {
    int t = threadIdx.x;
    int start = blockIdx.x * 128;
    int end = min(start + 128, NTOT);
    if (start >= end) return;
    auto bat = [&](int i) {
        return (i < NP) ? bp[i] : (i < NP + NF) ? bf[i - NP] : bpo[i - NP - NF];
    };
    float acc = 0.f;
    int g = bat(start);
    for (int i = start; i < end; ++i) {
        int gi = bat(i);
        if (gi != g) {
            atomicAdd(&pooled[(size_t)g * 128 + t], acc);
            acc = 0.f;
            g = gi;
        }
        acc += bf2f(X[(size_t)i * 128 + t]);
    }
    atomicAdd(&pooled[(size_t)g * 128 + t], acc);
}

// ---------------------------------------------------------------- final MLP
__global__ __launch_bounds__(128) void k_mlp(const float* __restrict__ pooled,
                                             const float* __restrict__ w1,
                                             const float* __restrict__ b1,
                                             const float* __restrict__ w2,
                                             const float* __restrict__ b2,
                                             float* __restrict__ out) {
    __shared__ float p[128];
    __shared__ float r0[2], r1[2];
    int g = blockIdx.x, t = threadIdx.x;
    p[t] = pooled[g * 128 + t];
    __syncthreads();
    float acc = b1[t];
    for (int k = 0; k < 128; ++k) acc = fmaf(p[k], w1[k * 128 + t], acc);
    float v0 = acc * w2[t * 2 + 0];
    float v1 = acc * w2[t * 2 + 1];
#pragma unroll
    for (int msk = 1; msk < 64; msk <<= 1) {
        v0 += __shfl_xor(v0, msk);
        v1 += __shfl_xor(v1, msk);
    }
    if ((t & 63) == 0) {
        r0[t >> 6] = v0;
        r1[t >> 6] = v1;
    }
    __syncthreads();
    if (t == 0) {
        out[g * 2 + 0] = r0[0] + r0[1] + b2[0];
        out[g * 2 + 1] = r1[0] + r1[1] + b2[1];
    }
}

// workspace-too-small diagnostic: report ws_size via the absmax channel
__global__ void k_ws_debug(float* out, int n, float val) {
    int i = blockIdx.x * 256 + threadIdx.x;
    if (i < n) out[i] = val;
}

// ---------------------------------------------------------------- launch
extern "C" void kernel_launch(void* const* d_in, const int* in_sizes, int n_in,
                              void* d_out, int out_size, void* d_ws, size_t ws_size,
                              hipStream_t stream) {
    const float* x_p0 = (const float*)d_in[0];
    const float* x_f0 = (const float*)d_in[1];
    const float* x_po0 = (const float*)d_in[2];
    const float* Wl[3] = {(const float*)d_in[3], (const float*)d_in[7],
                          (const float*)d_in[11]};
    const float* asl[3] = {(const float*)d_in[4], (const float*)d_in[8],
                           (const float*)d_in[12]};
    const float* adl[3] = {(const float*)d_in[5], (const float*)d_in[9],
                           (const float*)d_in[13]};
    const float* bl[3] = {(const float*)d_in[6], (const float*)d_in[10],
                          (const float*)d_in[14]};
    const float* lin1_w = (const float*)d_in[15];
    const float* lin1_b = (const float*)d_in[16];
    const float* lin2_w = (const float*)d_in[17];
    const float* lin2_b = (const float*)d_in[18];
    // relation order: 0..4 dst=process, 5..6 dst=file, 7..9 dst=port
    EiPtrs eis;
    eis.p[0] = (const int*)d_in[20];  // rev_access  (file -> proc)
    eis.p[1] = (const int*)d_in[22];  // rev_same_as (file -> proc)
    eis.p[2] = (const int*)d_in[24];  // rev_bind    (port -> proc)
    eis.p[3] = (const int*)d_in[27];  // create      (proc -> proc)
    eis.p[4] = (const int*)d_in[28];  // rev_create  (proc -> proc)
    eis.p[5] = (const int*)d_in[19];  // access      (proc -> file)
    eis.p[6] = (const int*)d_in[21];  // same_as     (proc -> file)
    eis.p[7] = (const int*)d_in[23];  // bind        (proc -> port)
    eis.p[8] = (const int*)d_in[25];  // session     (port -> port)
    eis.p[9] = (const int*)d_in[26];  // rev_session (port -> port)
    const int* batch_p = (const int*)d_in[29];
    const int* batch_f = (const int*)d_in[30];
    const int* batch_po = (const int*)d_in[31];
    float* out = (float*)d_out;

    // workspace layout (16B aligned)
    char* w = (char*)d_ws;
    size_t off = 0;
    int* offs = (int*)(w + off);      off += (size_t)850004 * 4;
    int* cursor = (int*)(w + off);    off += (size_t)TOTDEG * 4;
    int* list = (int*)(w + off);      off += (size_t)10 * E_EDGES * 4;
    int* bsum = (int*)(w + off);      off += 4096;
    unsigned short* H = (unsigned short*)(w + off); off += (size_t)NTOT * 128 * 2;
    unsigned short* X = (unsigned short*)(w + off); off += (size_t)NTOT * 128 * 2;
    float* s_all = (float*)(w + off); off += (size_t)NTOT * 4;
    float* d_all = (float*)(w + off); off += (size_t)NTOT * 4;
    float* pooled = (float*)(w + off); off += (size_t)GPOOL * 128 * 4;
    unsigned short* WT0 = (unsigned short*)(w + off); off += (size_t)128 * 64 * 2;
    unsigned short* WT1 = (unsigned short*)(w + off); off += (size_t)128 * 128 * 2;
    unsigned short* WT2 = (unsigned short*)(w + off); off += (size_t)128 * 128 * 2;
    unsigned short* wE = (unsigned short*)(w + off); off += (size_t)10 * E_EDGES * 2;
    if (ws_size < off) {
        k_ws_debug<<<(out_size + 255) / 256, 256, 0, stream>>>(out, out_size,
                                                               (float)ws_size);
        return;
    }

    k_init<<<(TOTDEG + 255) / 256, 256, 0, stream>>>(Wl[0], Wl[1], Wl[2], WT0, WT1, WT2,
                                                     cursor, pooled);

    int eb = (E_EDGES + 255) / 256;
    k_count_all<<<dim3(eb, 10, NPART_C), 256, 0, stream>>>(eis, cursor);
    int nb = (TOTDEG + 1 + 1023) / 1024;  // 831
    k_scan_partial<<<nb, 256, 0, stream>>>(cursor, bsum);
    k_scan_bsums<<<1, 1024, 0, stream>>>(bsum, nb);
    k_scan_final<<<nb, 256, 0, stream>>>(cursor, bsum, offs, cursor);
    k_fill_all<<<dim3(eb, 10, NPART_F), 256, 0, stream>>>(eis, cursor, list);

    for (int L = 0; L < 3; ++L) {
        if (L == 0) {
            gemm_l0<<<dim3((NP + 63) / 64, 3), 256, 0, stream>>>(
                x_p0, x_f0, x_po0, WT0, asl[0], adl[0], H, s_all, d_all);
        } else {
            const unsigned short* WTL = (L == 1) ? WT1 : WT2;
            gemm_big<<<(NTOT + 63) / 64, 256, 0, stream>>>(X, WTL, asl[L], adl[L], H,
                                                           s_all, d_all);
        }
        k_edgew<<<(TOTDEG + 255) / 256, 256, 0, stream>>>(offs, list, s_all, d_all, wE);
        k_gather<<<(NTOT + 7) / 8, 256, 0, stream>>>(offs, list, wE, bl[L], H, X);
    }

    pool_all<<<(NTOT + 127) / 128, 128, 0, stream>>>(X, batch_p, batch_f, batch_po,
                                                     pooled);

    k_mlp<<<GPOOL, 128, 0, stream>>>(pooled, lin1_w, lin1_b, lin2_w, lin2_b, out);
}